// Round 8
// baseline (322.813 us; speedup 1.0000x reference)
//
#include <hip/hip_runtime.h>

typedef __bf16 bf16;
typedef bf16 bf16x4 __attribute__((ext_vector_type(4)));
typedef bf16 bf16x8 __attribute__((ext_vector_type(8)));
typedef float floatx4 __attribute__((ext_vector_type(4)));
typedef unsigned int u32;

#define B_ 8
#define S_ 2048
#define I_ 1024
#define H_ 64

// async global->LDS 16B/lane: LDS dst = wave-uniform base + lane*16
__device__ __forceinline__ void async_cp16(bf16* lds_base, const bf16* g_base, int lane) {
    __builtin_amdgcn_global_load_lds(
        (const __attribute__((address_space(1))) u32*)(g_base + lane * 8),
        (__attribute__((address_space(3))) u32*)lds_base, 16, 0, 0);
}

// ---------------- Kernel A: fold scale + convert + pack W into B-frag lines ----
// Wf[(kc32*12 + ntile)*512 + (g*16 + nl)*8 + j] = W[ntile*16+nl][kc32*32 + g*8 + j]
// rows 0-63 = Wq*0.125, 64-127 = Wk, 128-191 = Wv. Each line = the exact 1KB
// B-fragment one wave loads with a single coalesced 16B/lane instruction.
__global__ void conv_w(const float* __restrict__ Wq, const float* __restrict__ bq,
                       const float* __restrict__ Wk, const float* __restrict__ bk,
                       const float* __restrict__ Wv, const float* __restrict__ bv,
                       bf16* __restrict__ Wf, float* __restrict__ bc) {
    int idx = blockIdx.x * 256 + threadIdx.x;   // 0 .. 192*1024-1
    int nrow = idx >> 10, i = idx & 1023;
    float v;
    if (nrow < 64)       v = Wq[nrow * I_ + i] * 0.125f;
    else if (nrow < 128) v = Wk[(nrow - 64) * I_ + i];
    else                 v = Wv[(nrow - 128) * I_ + i];
    int kc = i >> 5, t = i & 31, g = t >> 3, j = t & 7;
    int nt = nrow >> 4, nl = nrow & 15;
    Wf[(size_t)(kc * 12 + nt) * 512 + (g * 16 + nl) * 8 + j] = (bf16)v;
    if (idx < 192) {
        float bb = (idx < 64) ? bq[idx] * 0.125f
                 : (idx < 128) ? bk[idx - 64] : bv[idx - 128];
        bc[idx] = bb;
    }
}

// ---------------- Kernel B: QKV GEMM, X staged once, W from L2, 16 waves/CU ----
// Grid 1024 (M-tile 16), block 256 (4 waves). Wave w owns n-tiles w*3..w*3+2
// (N cols w*48..w*48+47). X (16x1024) -> LDS once (ONE barrier), then 32 k-steps
// reading W B-frag lines straight from L2. 96 MFMA/wave.
__global__ __launch_bounds__(256, 4) void qkv_gemm(const float* __restrict__ X,
                                                   const bf16* __restrict__ Wf,
                                                   const float* __restrict__ bc,
                                                   bf16* __restrict__ Qd,
                                                   bf16* __restrict__ Kd2,
                                                   bf16* __restrict__ Vt2) {
    __shared__ __align__(16) bf16 Xs[16 * 1032];   // 33 KB, stride 1032 (2-way banks)

    int tid = threadIdx.x;
    int w = tid >> 6, lane = tid & 63;
    int n = lane & 15, g = lane >> 4;
    int m0 = blockIdx.x * 16;

    floatx4 zero4 = {0.0f, 0.0f, 0.0f, 0.0f};
    floatx4 acc[3];
#pragma unroll
    for (int t = 0; t < 3; ++t) acc[t] = zero4;

    // ---- stage all X rows once: thread = (row = tid>>4, 16 float4 chunks) ----
    {
        int row = tid >> 4, cb = (tid & 15) * 4;
        const float* xr = X + (size_t)(m0 + row) * I_ + cb;
        bf16* xd = Xs + row * 1032 + cb;
#pragma unroll
        for (int q = 0; q < 16; ++q) {
            float4 v = *(const float4*)(xr + q * 64);
            bf16x4 xb;
            xb[0] = (bf16)v.x; xb[1] = (bf16)v.y; xb[2] = (bf16)v.z; xb[3] = (bf16)v.w;
            *(bf16x4*)(xd + q * 64) = xb;
        }
    }
    __syncthreads();   // the only barrier

    // ---- 32 k-steps of 32; W frags direct from L2 ----
    const bf16* wl = Wf + (size_t)(w * 3) * 512 + lane * 8;
    for (int ks = 0; ks < 32; ++ks) {
        bf16x8 xa = *(bf16x8*)(Xs + n * 1032 + ks * 32 + g * 8);
        const bf16* wrow = wl + (size_t)ks * 12 * 512;
#pragma unroll
        for (int nt = 0; nt < 3; ++nt) {
            bf16x8 wb = *(const bf16x8*)(wrow + nt * 512);
            acc[nt] = __builtin_amdgcn_mfma_f32_16x16x32_bf16(xa, wb, acc[nt], 0, 0, 0);
        }
    }

    // ---- epilogue: C/D layout col=lane&15, row=g*4+r ----
    int b = m0 >> 11;
    int sb = (m0 & 2047) + g * 4;
#pragma unroll
    for (int nt = 0; nt < 3; ++nt) {
        int ng = w * 48 + nt * 16 + n;
        float bias = bc[ng];
        if (ng < 64) {
#pragma unroll
            for (int r = 0; r < 4; ++r)
                Qd[(size_t)(b * S_ + sb + r) * H_ + ng] = (bf16)(acc[nt][r] + bias);
        } else if (ng < 128) {
            int hc = (ng - 64) >> 3, j = (ng - 64) & 7;
#pragma unroll
            for (int r = 0; r < 4; ++r)
                Kd2[((size_t)(b * 8 + hc) * S_ + sb + r) * 8 + j] = (bf16)(acc[nt][r] + bias);
        } else {
            int hh = ng - 128, kc = sb >> 3, jj = sb & 7;
            bf16x4 pk;
#pragma unroll
            for (int r = 0; r < 4; ++r) pk[r] = (bf16)(acc[nt][r] + bias);
            *(bf16x4*)(Vt2 + ((size_t)(b * 256 + kc) * 64 + hh) * 8 + jj) = pk;
        }
    }
}

// ---------------- Kernel C: flash attention, k-split x8, 24 waves/CU ----------------
// Grid 2048: bid = (b*32+qt)*8 + ksp. Block 256 (4 waves), q-tile 64, 256 k/block
// (2 iters of 128). K staged via async_cp16 into regA (aliased with Ps); V direct
// from global; mask = R3's batched scattered dwords (proven 68-VGPR core).
// LDS 17 KB only -> 6 blocks/CU at launch_bounds(256,6).
__global__ __launch_bounds__(256, 6) void attn(const bf16* __restrict__ Qd,
                                               const bf16* __restrict__ Kd2,
                                               const bf16* __restrict__ Vt2,
                                               const int* __restrict__ mask,
                                               float* __restrict__ po,
                                               float* __restrict__ pl) {
    __shared__ __align__(16) bf16 regA[8704];   // Ks (8*1040=8320) / Ps (64*136=8704)

    int tid = threadIdx.x;
    int w = tid >> 6, lane = tid & 63;
    int n = lane & 15, g = lane >> 4;
    int bid = blockIdx.x;
    int ksp = bid & 7;
    int qt = (bid >> 3) & 31;
    int b = bid >> 8;
    int q0 = qt * 64;

    const bf16* qptr = Qd + (size_t)(b * S_ + q0 + w * 16 + n) * H_ + g * 8;
    bf16x8 qa0 = *(const bf16x8*)qptr;
    bf16x8 qa1 = *(const bf16x8*)(qptr + 32);

    floatx4 zero4 = {0.0f, 0.0f, 0.0f, 0.0f};
    floatx4 o[4];
#pragma unroll
    for (int t = 0; t < 4; ++t) o[t] = zero4;
    float l_i[4] = {0.0f, 0.0f, 0.0f, 0.0f};

    const bf16* vp = Vt2 + (size_t)(b * 256) * 512;

    for (int kt = ksp * 2; kt < ksp * 2 + 2; ++kt) {
        // ---- batched mask dwords (exactly-once traffic, 64B segments) ----
        const int* mb = mask + (size_t)(b * S_ + q0 + w * 16 + g * 4) * S_ + kt * 128 + n;
        int mreg[4][8];
#pragma unroll
        for (int r = 0; r < 4; ++r)
#pragma unroll
            for (int nt = 0; nt < 8; ++nt)
                mreg[r][nt] = mb[(size_t)r * S_ + nt * 16];
        // ---- async stage K (8 h-chunks x 2KB) ----
#pragma unroll
        for (int j = 0; j < 2; ++j) {
            int hc = w * 2 + j;
#pragma unroll
            for (int p = 0; p < 2; ++p)
                async_cp16(regA + hc * 1040 + p * 512,
                           Kd2 + ((size_t)(b * 8 + hc) * S_ + kt * 128 + p * 64) * 8, lane);
        }
        __syncthreads();   // b1: K staged

        // ---- S = Q K^T ----
        floatx4 s[8];
#pragma unroll
        for (int nt = 0; nt < 8; ++nt) {
            floatx4 a = zero4;
            a = __builtin_amdgcn_mfma_f32_16x16x32_bf16(
                    qa0, *(const bf16x8*)(regA + g * 1040 + (nt * 16 + n) * 8), a, 0, 0, 0);
            a = __builtin_amdgcn_mfma_f32_16x16x32_bf16(
                    qa1, *(const bf16x8*)(regA + (4 + g) * 1040 + (nt * 16 + n) * 8), a, 0, 0, 0);
            s[nt] = a;
        }

        // ---- p = mask ? exp(s) : 0 (scores bounded; no max subtraction) ----
#pragma unroll
        for (int r = 0; r < 4; ++r)
#pragma unroll
            for (int nt = 0; nt < 8; ++nt) {
                float e = __expf(s[nt][r]);
                float p = (mreg[r][nt] != 0) ? e : 0.0f;
                s[nt][r] = p;
                l_i[r] += p;
            }
        __syncthreads();   // b2: K reads done before P overwrite

        // ---- P: C-layout -> LDS (aliased over K region) ----
#pragma unroll
        for (int r = 0; r < 4; ++r)
#pragma unroll
            for (int nt = 0; nt < 8; ++nt)
                regA[(w * 16 + g * 4 + r) * 136 + nt * 16 + n] = (bf16)s[nt][r];
        __syncthreads();   // b3: P visible

        // ---- O += P V : V frags direct from global ----
#pragma unroll
        for (int k0 = 0; k0 < 4; ++k0) {
            bf16x8 pa = *(bf16x8*)(regA + (w * 16 + n) * 136 + k0 * 32 + g * 8);
#pragma unroll
            for (int ht = 0; ht < 4; ++ht) {
                bf16x8 vb = *(const bf16x8*)(vp +
                    ((size_t)(kt * 16 + k0 * 4 + g) * 64 + ht * 16 + n) * 8);
                o[ht] = __builtin_amdgcn_mfma_f32_16x16x32_bf16(pa, vb, o[ht], 0, 0, 0);
            }
        }
        __syncthreads();   // b4: P reads done before next K staging
    }

    // ---- final row-sum reduce (once) ----
#pragma unroll
    for (int r = 0; r < 4; ++r)
#pragma unroll
        for (int off = 1; off < 16; off <<= 1)
            l_i[r] += __shfl_xor(l_i[r], off, 64);

    float* pb = po + (size_t)bid * 4096;
#pragma unroll
    for (int ht = 0; ht < 4; ++ht)
#pragma unroll
        for (int r = 0; r < 4; ++r)
            pb[(w * 16 + g * 4 + r) * 64 + ht * 16 + n] = o[ht][r];
    if (n == 0) {
#pragma unroll
        for (int r = 0; r < 4; ++r)
            pl[(size_t)bid * 64 + w * 16 + g * 4 + r] = l_i[r];
    }
}

// ---------------- Kernel D: merge 8 k-split partials (plain sums) ----------------
__global__ __launch_bounds__(256) void reduce_o(const float* __restrict__ po,
                                                const float* __restrict__ pl,
                                                float* __restrict__ out) {
    int idx = blockIdx.x * 256 + threadIdx.x;   // (q,h): 16384*64
    int h = idx & 63, q = idx >> 6;
    int b = q >> 11, qq = q & 2047;
    int qt = qq >> 6, ql = qq & 63;
    int bid0 = (b * 32 + qt) * 8;
    float num = 0.0f, den = 0.0f;
#pragma unroll
    for (int j = 0; j < 8; ++j) {
        den += pl[(size_t)(bid0 + j) * 64 + ql];
        num += po[(size_t)(bid0 + j) * 4096 + ql * 64 + h];
    }
    out[(size_t)q * 64 + h] = num / den;
}

extern "C" void kernel_launch(void* const* d_in, const int* in_sizes, int n_in,
                              void* d_out, int out_size, void* d_ws, size_t ws_size,
                              hipStream_t stream) {
    const float* X    = (const float*)d_in[0];
    const int*   mask = (const int*)d_in[1];
    const float* Wq   = (const float*)d_in[2];
    const float* bq   = (const float*)d_in[3];
    const float* Wk   = (const float*)d_in[4];
    const float* bk   = (const float*)d_in[5];
    const float* Wv   = (const float*)d_in[6];
    const float* bv   = (const float*)d_in[7];
    float* out = (float*)d_out;

    char* p = (char*)d_ws;
    bf16* Qd   = (bf16*)p;  p += (size_t)B_ * S_ * H_ * 2;      // 2 MB
    bf16* Kd2  = (bf16*)p;  p += (size_t)B_ * S_ * H_ * 2;      // 2 MB
    bf16* Vt2  = (bf16*)p;  p += (size_t)B_ * S_ * H_ * 2;      // 2 MB
    bf16* Wf   = (bf16*)p;  p += (size_t)192 * 1024 * 2;        // 384 KB packed W
    float* bc  = (float*)p; p += 1024;
    float* po  = (float*)p; p += (size_t)2048 * 4096 * 4;       // 32 MB
    float* pl  = (float*)p; p += (size_t)2048 * 64 * 4;         // 512 KB

    conv_w<<<dim3(768), dim3(256), 0, stream>>>(Wq, bq, Wk, bk, Wv, bv, Wf, bc);
    qkv_gemm<<<dim3(1024), dim3(256), 0, stream>>>(X, Wf, bc, Qd, Kd2, Vt2);
    attn<<<dim3(2048), dim3(256), 0, stream>>>(Qd, Kd2, Vt2, mask, po, pl);
    reduce_o<<<dim3(4096), dim3(256), 0, stream>>>(po, pl, out);
}